// Round 5
// baseline (2728.418 us; speedup 1.0000x reference)
//
#include <hip/hip_runtime.h>
#include <math.h>

#define N_NODES 100000
#define LN_EPS 1e-5f

// ---------------- small utility kernels ----------------
__global__ void zero_int(int* __restrict__ p, int n) {
    int i = blockIdx.x * blockDim.x + threadIdx.x;
    if (i < n) p[i] = 0;
}

__global__ void set_int(int* __restrict__ p, int v) {
    if (threadIdx.x == 0 && blockIdx.x == 0) *p = v;
}

__global__ void hist_dst(const int* __restrict__ dst, int* __restrict__ deg, int E) {
    int e = blockIdx.x * blockDim.x + threadIdx.x;
    if (e < E) atomicAdd(&deg[dst[e]], 1);
}

__global__ void deg_to_dinv(const int* __restrict__ deg, float* __restrict__ dinv, int n) {
    int i = blockIdx.x * blockDim.x + threadIdx.x;
    if (i < n) dinv[i] = rsqrtf((float)deg[i] + 1.f);
}

// exclusive scan, 256 elems/block
__global__ void scan_block(const int* __restrict__ in, int* __restrict__ out,
                           int* __restrict__ bsums, int n) {
    __shared__ int s[256];
    int i = blockIdx.x * 256 + threadIdx.x;
    int v = (i < n) ? in[i] : 0;
    s[threadIdx.x] = v;
    __syncthreads();
    for (int off = 1; off < 256; off <<= 1) {
        int t = ((int)threadIdx.x >= off) ? s[threadIdx.x - off] : 0;
        __syncthreads();
        s[threadIdx.x] += t;
        __syncthreads();
    }
    if (i < n) out[i] = s[threadIdx.x] - v;  // exclusive
    if (threadIdx.x == 255) bsums[blockIdx.x] = s[255];
}

__global__ void scan_sums(int* __restrict__ bsums, int nb) {
    if (threadIdx.x == 0 && blockIdx.x == 0) {
        int acc = 0;
        for (int i = 0; i < nb; ++i) { int t = bsums[i]; bsums[i] = acc; acc += t; }
    }
}

__global__ void scan_add(int* __restrict__ out, const int* __restrict__ bsums, int n) {
    int i = blockIdx.x * 256 + threadIdx.x;
    if (i < n) out[i] += bsums[blockIdx.x];
}

__global__ void fill_csr(const int* __restrict__ src, const int* __restrict__ dst,
                         const int* __restrict__ offsets, int* __restrict__ cursor,
                         int* __restrict__ csr_src, int E) {
    int e = blockIdx.x * blockDim.x + threadIdx.x;
    if (e < E) {
        int d = dst[e];
        int pos = offsets[d] + atomicAdd(&cursor[d], 1);
        csr_src[pos] = src[e];
    }
}

// ---------------- LDS-staged wave-cooperative gemm (+bias+LN+ELU) ----------------
// NPW=8: keeps acc + in-flight ds_read under 128 VGPRs (R4's NPW=16 hit the
// 256-VGPR ceiling and spilled ~400MB scratch per launch).
template <int IN_C, int OUT_C, int NPW, bool LN, bool BIAS>
__launch_bounds__(256, 4)
__global__ void gemm_tile(const float* __restrict__ X, const float* __restrict__ W,
                          const float* __restrict__ bias, const float* __restrict__ gamma,
                          const float* __restrict__ beta, float* __restrict__ Y, int n) {
    constexpr int LPN = (OUT_C < 64) ? OUT_C : 64;  // lanes per node-group
    constexpr int G   = 64 / LPN;                   // node groups per wave
    constexpr int JPL = (OUT_C + 63) / 64;          // cols per lane
    constexpr int NW  = 4;                          // waves per block
    constexpr int NPWG = NPW * G;                   // nodes per wave
    constexpr int C4  = IN_C / 4;

    __shared__ float sW[IN_C * OUT_C];
    __shared__ float4 sX[NW][NPWG * C4];

    for (int i = threadIdx.x; i < IN_C * OUT_C; i += 256) sW[i] = W[i];

    int wv = threadIdx.x >> 6, lane = threadIdx.x & 63;
    int g = lane / LPN;
    int col = lane % LPN;
    int nb = (blockIdx.x * NW + wv) * NPWG;  // wave's first node

    // stage x rows [nb, nb+NPWG) -- coalesced float4
    const float4* X4 = (const float4*)X;
#pragma unroll
    for (int i = 0; i < NPWG * C4 / 64; ++i) {
        int idx = i * 64 + lane;
        int row = idx / C4, c4 = idx % C4;
        int node = nb + row;
        node = (node < n) ? node : (n - 1);
        sX[wv][idx] = X4[(size_t)node * C4 + c4];
    }
    __syncthreads();  // sW ready (sX is wave-private)

    float acc[NPW][JPL];
#pragma unroll
    for (int m = 0; m < NPW; ++m)
#pragma unroll
        for (int jj = 0; jj < JPL; ++jj) acc[m][jj] = 0.f;

    for (int k4 = 0; k4 < C4; ++k4) {
        float wf[4][JPL];
#pragma unroll
        for (int kk = 0; kk < 4; ++kk)
#pragma unroll
            for (int jj = 0; jj < JPL; ++jj)
                wf[kk][jj] = sW[(k4 * 4 + kk) * OUT_C + col + jj * 64];
#pragma unroll 4
        for (int m = 0; m < NPW; ++m) {
            float4 xv = sX[wv][(g * NPW + m) * C4 + k4];  // broadcast within group
#pragma unroll
            for (int kk = 0; kk < 4; ++kk) {
                float xs = (kk == 0) ? xv.x : (kk == 1) ? xv.y : (kk == 2) ? xv.z : xv.w;
#pragma unroll
                for (int jj = 0; jj < JPL; ++jj) acc[m][jj] += xs * wf[kk][jj];
            }
        }
    }

    // epilogue
    float bj[JPL], gj[JPL], btj[JPL];
#pragma unroll
    for (int jj = 0; jj < JPL; ++jj) {
        int c = col + jj * 64;
        bj[jj]  = BIAS ? bias[c] : 0.f;
        gj[jj]  = LN ? gamma[c] : 1.f;
        btj[jj] = LN ? beta[c] : 0.f;
    }
#pragma unroll
    for (int m = 0; m < NPW; ++m) {
        int node = nb + g * NPW + m;
        if (LN) {
            float v[JPL];
            float s = 0.f, sq = 0.f;
#pragma unroll
            for (int jj = 0; jj < JPL; ++jj) {
                v[jj] = acc[m][jj] + bj[jj];
                s += v[jj];
                sq += v[jj] * v[jj];
            }
#pragma unroll
            for (int off = LPN / 2; off > 0; off >>= 1) {
                s += __shfl_xor(s, off, 64);
                sq += __shfl_xor(sq, off, 64);
            }
            float mu = s / OUT_C;
            float var = sq / OUT_C - mu * mu;
            float rs = rsqrtf(var + LN_EPS);
            if (node < n) {
#pragma unroll
                for (int jj = 0; jj < JPL; ++jj) {
                    float y = (v[jj] - mu) * rs * gj[jj] + btj[jj];
                    Y[(size_t)node * OUT_C + col + jj * 64] = y > 0.f ? y : expm1f(y);
                }
            }
        } else if (node < n) {
#pragma unroll
            for (int jj = 0; jj < JPL; ++jj)
                Y[(size_t)node * OUT_C + col + jj * 64] = acc[m][jj] + bj[jj];
        }
    }
}

// ---------------- fused gather (+ self loop) [+ bias + LN + ELU] ----------------
template <bool LN>
__global__ void gather64(const float* __restrict__ xw, const int* __restrict__ offsets,
                         const int* __restrict__ csr_src, const float* __restrict__ dinv,
                         const float* __restrict__ bias, const float* __restrict__ gamma,
                         const float* __restrict__ beta, float* __restrict__ out, int n) {
    int wave = threadIdx.x >> 6;
    int lane = threadIdx.x & 63;
    int node = blockIdx.x * (blockDim.x >> 6) + wave;
    if (node >= n) return;
    int beg = offsets[node], end = offsets[node + 1];

    float acc = 0.f;
    for (int base = beg; base < end; base += 64) {
        int m = min(64, end - base);
        int myS = (lane < m) ? csr_src[base + lane] : 0;
        float myN = (lane < m) ? dinv[myS] : 0.f;
        int j = 0;
        for (; j + 4 <= m; j += 4) {
            int s0 = __shfl(myS, j, 64), s1 = __shfl(myS, j + 1, 64);
            int s2 = __shfl(myS, j + 2, 64), s3 = __shfl(myS, j + 3, 64);
            float n0 = __shfl(myN, j, 64), n1 = __shfl(myN, j + 1, 64);
            float n2 = __shfl(myN, j + 2, 64), n3 = __shfl(myN, j + 3, 64);
            float r0 = xw[(size_t)s0 * 64 + lane];
            float r1 = xw[(size_t)s1 * 64 + lane];
            float r2 = xw[(size_t)s2 * 64 + lane];
            float r3 = xw[(size_t)s3 * 64 + lane];
            acc += r0 * n0;
            acc += r1 * n1;
            acc += r2 * n2;
            acc += r3 * n3;
        }
        for (; j < m; ++j) {
            int s = __shfl(myS, j, 64);
            float nm = __shfl(myN, j, 64);
            acc += xw[(size_t)s * 64 + lane] * nm;
        }
    }

    float dd = dinv[node];
    float y = acc * dd + xw[(size_t)node * 64 + lane] * dd * dd;
    if (!LN) {
        out[(size_t)node * 64 + lane] = y;
        return;
    }
    y += bias[lane];
    float s = y, sq = y * y;
#pragma unroll
    for (int off = 32; off > 0; off >>= 1) {
        s += __shfl_xor(s, off, 64);
        sq += __shfl_xor(sq, off, 64);
    }
    float mu = s / 64.f;
    float var = sq / 64.f - mu * mu;
    float rs = rsqrtf(var + LN_EPS);
    float z = (y - mu) * rs * gamma[lane] + beta[lane];
    out[(size_t)node * 64 + lane] = z > 0.f ? z : expm1f(z);
}

extern "C" void kernel_launch(void* const* d_in, const int* in_sizes, int n_in,
                              void* d_out, int out_size, void* d_ws, size_t ws_size,
                              hipStream_t stream) {
    const float* x  = (const float*)d_in[0];
    const int* ei   = (const int*)d_in[1];
    const float* W1 = (const float*)d_in[2];
    const float* b1 = (const float*)d_in[3];
    const float* g1 = (const float*)d_in[4];
    const float* be1= (const float*)d_in[5];
    const float* W2 = (const float*)d_in[6];
    const float* b2 = (const float*)d_in[7];
    const float* g2 = (const float*)d_in[8];
    const float* be2= (const float*)d_in[9];
    const float* W3 = (const float*)d_in[10];
    const float* b3 = (const float*)d_in[11];
    const float* g3 = (const float*)d_in[12];
    const float* be3= (const float*)d_in[13];
    const float* lw1= (const float*)d_in[14];
    const float* lb1= (const float*)d_in[15];
    const float* g4 = (const float*)d_in[16];
    const float* be4= (const float*)d_in[17];
    const float* lw2= (const float*)d_in[18];
    const float* lb2= (const float*)d_in[19];
    float* out = (float*)d_out;

    const int E = in_sizes[1] / 2;
    const int* src = ei;
    const int* dst = ei + E;
    const int N = N_NODES;

    // workspace layout
    float* bufA    = (float*)d_ws;                    // N*128
    float* bufB    = bufA + (size_t)N * 128;          // N*128
    float* dinv    = bufB + (size_t)N * 128;          // N
    int*   deg     = (int*)(dinv + N);                // N
    int*   offsets = deg + N;                         // N+1
    int*   cursor  = offsets + N + 1;                 // N
    int*   csr     = cursor + N;                      // E
    int*   bsums   = csr + E;                         // ceil(N/256)

    auto cdiv = [](long long a, long long b) { return (int)((a + b - 1) / b); };
    const int NB = cdiv(N, 256);

    // ---- build CSR (dst-sorted) + dinv ----
    zero_int<<<NB, 256, 0, stream>>>(deg, N);
    zero_int<<<NB, 256, 0, stream>>>(cursor, N);
    hist_dst<<<cdiv(E, 256), 256, 0, stream>>>(dst, deg, E);
    scan_block<<<NB, 256, 0, stream>>>(deg, offsets, bsums, N);
    scan_sums<<<1, 64, 0, stream>>>(bsums, NB);
    scan_add<<<NB, 256, 0, stream>>>(offsets, bsums, N);
    set_int<<<1, 64, 0, stream>>>(offsets + N, E);
    fill_csr<<<cdiv(E, 256), 256, 0, stream>>>(src, dst, offsets, cursor, csr, E);
    deg_to_dinv<<<NB, 256, 0, stream>>>(deg, dinv, N);

    // ---- Layer 1: xw1 = x @ W1 (128->64); h1 = LN_ELU(gather + b1) ----
    gemm_tile<128, 64, 8, false, false><<<cdiv(N, 32), 256, 0, stream>>>(
        x, W1, nullptr, nullptr, nullptr, bufA, N);
    gather64<true><<<cdiv(N, 4), 256, 0, stream>>>(bufA, offsets, csr, dinv, b1, g1, be1, bufB, N);

    // ---- Layer 2 (aggregate-first): a2 = gather(h1); h2 = LN_ELU(a2 @ W2 + b2) ----
    gather64<false><<<cdiv(N, 4), 256, 0, stream>>>(bufB, offsets, csr, dinv, nullptr, nullptr, nullptr, bufA, N);
    gemm_tile<64, 128, 8, true, true><<<cdiv(N, 32), 256, 0, stream>>>(
        bufA, W2, b2, g2, be2, bufB, N);

    // ---- Layer 3: xw3 = h2 @ W3 (128->64); h3 = LN_ELU(gather + b3) ----
    gemm_tile<128, 64, 8, false, false><<<cdiv(N, 32), 256, 0, stream>>>(
        bufB, W3, nullptr, nullptr, nullptr, bufA, N);
    gather64<true><<<cdiv(N, 4), 256, 0, stream>>>(bufA, offsets, csr, dinv, b3, g3, be3, bufB, N);

    // ---- lin1: t = LN_ELU(h3 @ lw1 + lb1) (64->32) ----
    gemm_tile<64, 32, 8, true, true><<<cdiv(N, 64), 256, 0, stream>>>(
        bufB, lw1, lb1, g4, be4, bufA, N);

    // ---- lin2: out = t @ lw2 + lb2 (32->32) ----
    gemm_tile<32, 32, 8, false, true><<<cdiv(N, 64), 256, 0, stream>>>(
        bufA, lw2, lb2, nullptr, nullptr, out, N);
}

// Round 6
// 1611.965 us; speedup vs baseline: 1.6926x; 1.6926x over previous
//
#include <hip/hip_runtime.h>
#include <math.h>

#define N_NODES 100000
#define LN_EPS 1e-5f

// ---------------- small utility kernels ----------------
__global__ void zero_int(int* __restrict__ p, int n) {
    int i = blockIdx.x * blockDim.x + threadIdx.x;
    if (i < n) p[i] = 0;
}

__global__ void set_int(int* __restrict__ p, int v) {
    if (threadIdx.x == 0 && blockIdx.x == 0) *p = v;
}

__global__ void hist_dst(const int* __restrict__ dst, int* __restrict__ deg, int E) {
    int e = blockIdx.x * blockDim.x + threadIdx.x;
    if (e < E) atomicAdd(&deg[dst[e]], 1);
}

__global__ void deg_to_dinv(const int* __restrict__ deg, float* __restrict__ dinv, int n) {
    int i = blockIdx.x * blockDim.x + threadIdx.x;
    if (i < n) dinv[i] = rsqrtf((float)deg[i] + 1.f);
}

// exclusive scan, 256 elems/block
__global__ void scan_block(const int* __restrict__ in, int* __restrict__ out,
                           int* __restrict__ bsums, int n) {
    __shared__ int s[256];
    int i = blockIdx.x * 256 + threadIdx.x;
    int v = (i < n) ? in[i] : 0;
    s[threadIdx.x] = v;
    __syncthreads();
    for (int off = 1; off < 256; off <<= 1) {
        int t = ((int)threadIdx.x >= off) ? s[threadIdx.x - off] : 0;
        __syncthreads();
        s[threadIdx.x] += t;
        __syncthreads();
    }
    if (i < n) out[i] = s[threadIdx.x] - v;  // exclusive
    if (threadIdx.x == 255) bsums[blockIdx.x] = s[255];
}

__global__ void scan_sums(int* __restrict__ bsums, int nb) {
    if (threadIdx.x == 0 && blockIdx.x == 0) {
        int acc = 0;
        for (int i = 0; i < nb; ++i) { int t = bsums[i]; bsums[i] = acc; acc += t; }
    }
}

__global__ void scan_add(int* __restrict__ out, const int* __restrict__ bsums, int n) {
    int i = blockIdx.x * 256 + threadIdx.x;
    if (i < n) out[i] += bsums[blockIdx.x];
}

__global__ void fill_csr(const int* __restrict__ src, const int* __restrict__ dst,
                         const int* __restrict__ offsets, int* __restrict__ cursor,
                         int* __restrict__ csr_src, int E) {
    int e = blockIdx.x * blockDim.x + threadIdx.x;
    if (e < E) {
        int d = dst[e];
        int pos = offsets[d] + atomicAdd(&cursor[d], 1);
        csr_src[pos] = src[e];
    }
}

// ---------------- LDS-staged wave-cooperative gemm (+bias+LN+ELU) ----------------
// NPW=8 keeps register demand low; NO min-occupancy launch_bounds hint:
// R5's (256,4) squeezed the allocator to 64 VGPRs -> 4.8GB scratch spill.
template <int IN_C, int OUT_C, int NPW, bool LN, bool BIAS>
__launch_bounds__(256)
__global__ void gemm_tile(const float* __restrict__ X, const float* __restrict__ W,
                          const float* __restrict__ bias, const float* __restrict__ gamma,
                          const float* __restrict__ beta, float* __restrict__ Y, int n) {
    constexpr int LPN = (OUT_C < 64) ? OUT_C : 64;  // lanes per node-group
    constexpr int G   = 64 / LPN;                   // node groups per wave
    constexpr int JPL = (OUT_C + 63) / 64;          // cols per lane
    constexpr int NW  = 4;                          // waves per block
    constexpr int NPWG = NPW * G;                   // nodes per wave
    constexpr int C4  = IN_C / 4;

    __shared__ float sW[IN_C * OUT_C];
    __shared__ float4 sX[NW][NPWG * C4];

    for (int i = threadIdx.x; i < IN_C * OUT_C; i += 256) sW[i] = W[i];

    int wv = threadIdx.x >> 6, lane = threadIdx.x & 63;
    int g = lane / LPN;
    int col = lane % LPN;
    int nb = (blockIdx.x * NW + wv) * NPWG;  // wave's first node

    // stage x rows [nb, nb+NPWG) -- coalesced float4
    const float4* X4 = (const float4*)X;
#pragma unroll
    for (int i = 0; i < NPWG * C4 / 64; ++i) {
        int idx = i * 64 + lane;
        int row = idx / C4, c4 = idx % C4;
        int node = nb + row;
        node = (node < n) ? node : (n - 1);
        sX[wv][idx] = X4[(size_t)node * C4 + c4];
    }
    __syncthreads();  // sW ready (sX is wave-private)

    float acc[NPW][JPL];
#pragma unroll
    for (int m = 0; m < NPW; ++m)
#pragma unroll
        for (int jj = 0; jj < JPL; ++jj) acc[m][jj] = 0.f;

    for (int k4 = 0; k4 < C4; ++k4) {
        float wf[4][JPL];
#pragma unroll
        for (int kk = 0; kk < 4; ++kk)
#pragma unroll
            for (int jj = 0; jj < JPL; ++jj)
                wf[kk][jj] = sW[(k4 * 4 + kk) * OUT_C + col + jj * 64];
#pragma unroll 4
        for (int m = 0; m < NPW; ++m) {
            float4 xv = sX[wv][(g * NPW + m) * C4 + k4];  // broadcast within group
#pragma unroll
            for (int kk = 0; kk < 4; ++kk) {
                float xs = (kk == 0) ? xv.x : (kk == 1) ? xv.y : (kk == 2) ? xv.z : xv.w;
#pragma unroll
                for (int jj = 0; jj < JPL; ++jj) acc[m][jj] += xs * wf[kk][jj];
            }
        }
    }

    // epilogue
    float bj[JPL], gj[JPL], btj[JPL];
#pragma unroll
    for (int jj = 0; jj < JPL; ++jj) {
        int c = col + jj * 64;
        bj[jj]  = BIAS ? bias[c] : 0.f;
        gj[jj]  = LN ? gamma[c] : 1.f;
        btj[jj] = LN ? beta[c] : 0.f;
    }
#pragma unroll
    for (int m = 0; m < NPW; ++m) {
        int node = nb + g * NPW + m;
        if (LN) {
            float v[JPL];
            float s = 0.f, sq = 0.f;
#pragma unroll
            for (int jj = 0; jj < JPL; ++jj) {
                v[jj] = acc[m][jj] + bj[jj];
                s += v[jj];
                sq += v[jj] * v[jj];
            }
#pragma unroll
            for (int off = LPN / 2; off > 0; off >>= 1) {
                s += __shfl_xor(s, off, 64);
                sq += __shfl_xor(sq, off, 64);
            }
            float mu = s / OUT_C;
            float var = sq / OUT_C - mu * mu;
            float rs = rsqrtf(var + LN_EPS);
            if (node < n) {
#pragma unroll
                for (int jj = 0; jj < JPL; ++jj) {
                    float y = (v[jj] - mu) * rs * gj[jj] + btj[jj];
                    Y[(size_t)node * OUT_C + col + jj * 64] = y > 0.f ? y : expm1f(y);
                }
            }
        } else if (node < n) {
#pragma unroll
            for (int jj = 0; jj < JPL; ++jj)
                Y[(size_t)node * OUT_C + col + jj * 64] = acc[m][jj] + bj[jj];
        }
    }
}

// ---------------- fused gather (+ self loop) [+ bias + LN + ELU] ----------------
template <bool LN>
__global__ void gather64(const float* __restrict__ xw, const int* __restrict__ offsets,
                         const int* __restrict__ csr_src, const float* __restrict__ dinv,
                         const float* __restrict__ bias, const float* __restrict__ gamma,
                         const float* __restrict__ beta, float* __restrict__ out, int n) {
    int wave = threadIdx.x >> 6;
    int lane = threadIdx.x & 63;
    int node = blockIdx.x * (blockDim.x >> 6) + wave;
    if (node >= n) return;
    int beg = offsets[node], end = offsets[node + 1];

    float acc = 0.f;
    for (int base = beg; base < end; base += 64) {
        int m = min(64, end - base);
        int myS = (lane < m) ? csr_src[base + lane] : 0;
        float myN = (lane < m) ? dinv[myS] : 0.f;
        int j = 0;
        for (; j + 4 <= m; j += 4) {
            int s0 = __shfl(myS, j, 64), s1 = __shfl(myS, j + 1, 64);
            int s2 = __shfl(myS, j + 2, 64), s3 = __shfl(myS, j + 3, 64);
            float n0 = __shfl(myN, j, 64), n1 = __shfl(myN, j + 1, 64);
            float n2 = __shfl(myN, j + 2, 64), n3 = __shfl(myN, j + 3, 64);
            float r0 = xw[(size_t)s0 * 64 + lane];
            float r1 = xw[(size_t)s1 * 64 + lane];
            float r2 = xw[(size_t)s2 * 64 + lane];
            float r3 = xw[(size_t)s3 * 64 + lane];
            acc += r0 * n0;
            acc += r1 * n1;
            acc += r2 * n2;
            acc += r3 * n3;
        }
        for (; j < m; ++j) {
            int s = __shfl(myS, j, 64);
            float nm = __shfl(myN, j, 64);
            acc += xw[(size_t)s * 64 + lane] * nm;
        }
    }

    float dd = dinv[node];
    float y = acc * dd + xw[(size_t)node * 64 + lane] * dd * dd;
    if (!LN) {
        out[(size_t)node * 64 + lane] = y;
        return;
    }
    y += bias[lane];
    float s = y, sq = y * y;
#pragma unroll
    for (int off = 32; off > 0; off >>= 1) {
        s += __shfl_xor(s, off, 64);
        sq += __shfl_xor(sq, off, 64);
    }
    float mu = s / 64.f;
    float var = sq / 64.f - mu * mu;
    float rs = rsqrtf(var + LN_EPS);
    float z = (y - mu) * rs * gamma[lane] + beta[lane];
    out[(size_t)node * 64 + lane] = z > 0.f ? z : expm1f(z);
}

extern "C" void kernel_launch(void* const* d_in, const int* in_sizes, int n_in,
                              void* d_out, int out_size, void* d_ws, size_t ws_size,
                              hipStream_t stream) {
    const float* x  = (const float*)d_in[0];
    const int* ei   = (const int*)d_in[1];
    const float* W1 = (const float*)d_in[2];
    const float* b1 = (const float*)d_in[3];
    const float* g1 = (const float*)d_in[4];
    const float* be1= (const float*)d_in[5];
    const float* W2 = (const float*)d_in[6];
    const float* b2 = (const float*)d_in[7];
    const float* g2 = (const float*)d_in[8];
    const float* be2= (const float*)d_in[9];
    const float* W3 = (const float*)d_in[10];
    const float* b3 = (const float*)d_in[11];
    const float* g3 = (const float*)d_in[12];
    const float* be3= (const float*)d_in[13];
    const float* lw1= (const float*)d_in[14];
    const float* lb1= (const float*)d_in[15];
    const float* g4 = (const float*)d_in[16];
    const float* be4= (const float*)d_in[17];
    const float* lw2= (const float*)d_in[18];
    const float* lb2= (const float*)d_in[19];
    float* out = (float*)d_out;

    const int E = in_sizes[1] / 2;
    const int* src = ei;
    const int* dst = ei + E;
    const int N = N_NODES;

    // workspace layout
    float* bufA    = (float*)d_ws;                    // N*128
    float* bufB    = bufA + (size_t)N * 128;          // N*128
    float* dinv    = bufB + (size_t)N * 128;          // N
    int*   deg     = (int*)(dinv + N);                // N
    int*   offsets = deg + N;                         // N+1
    int*   cursor  = offsets + N + 1;                 // N
    int*   csr     = cursor + N;                      // E
    int*   bsums   = csr + E;                         // ceil(N/256)

    auto cdiv = [](long long a, long long b) { return (int)((a + b - 1) / b); };
    const int NB = cdiv(N, 256);

    // ---- build CSR (dst-sorted) + dinv ----
    zero_int<<<NB, 256, 0, stream>>>(deg, N);
    zero_int<<<NB, 256, 0, stream>>>(cursor, N);
    hist_dst<<<cdiv(E, 256), 256, 0, stream>>>(dst, deg, E);
    scan_block<<<NB, 256, 0, stream>>>(deg, offsets, bsums, N);
    scan_sums<<<1, 64, 0, stream>>>(bsums, NB);
    scan_add<<<NB, 256, 0, stream>>>(offsets, bsums, N);
    set_int<<<1, 64, 0, stream>>>(offsets + N, E);
    fill_csr<<<cdiv(E, 256), 256, 0, stream>>>(src, dst, offsets, cursor, csr, E);
    deg_to_dinv<<<NB, 256, 0, stream>>>(deg, dinv, N);

    // ---- Layer 1: xw1 = x @ W1 (128->64); h1 = LN_ELU(gather + b1) ----
    gemm_tile<128, 64, 8, false, false><<<cdiv(N, 32), 256, 0, stream>>>(
        x, W1, nullptr, nullptr, nullptr, bufA, N);
    gather64<true><<<cdiv(N, 4), 256, 0, stream>>>(bufA, offsets, csr, dinv, b1, g1, be1, bufB, N);

    // ---- Layer 2 (aggregate-first): a2 = gather(h1); h2 = LN_ELU(a2 @ W2 + b2) ----
    gather64<false><<<cdiv(N, 4), 256, 0, stream>>>(bufB, offsets, csr, dinv, nullptr, nullptr, nullptr, bufA, N);
    gemm_tile<64, 128, 8, true, true><<<cdiv(N, 32), 256, 0, stream>>>(
        bufA, W2, b2, g2, be2, bufB, N);

    // ---- Layer 3: xw3 = h2 @ W3 (128->64); h3 = LN_ELU(gather + b3) ----
    gemm_tile<128, 64, 8, false, false><<<cdiv(N, 32), 256, 0, stream>>>(
        bufB, W3, nullptr, nullptr, nullptr, bufA, N);
    gather64<true><<<cdiv(N, 4), 256, 0, stream>>>(bufA, offsets, csr, dinv, b3, g3, be3, bufB, N);

    // ---- lin1: t = LN_ELU(h3 @ lw1 + lb1) (64->32) ----
    gemm_tile<64, 32, 8, true, true><<<cdiv(N, 64), 256, 0, stream>>>(
        bufB, lw1, lb1, g4, be4, bufA, N);

    // ---- lin2: out = t @ lw2 + lb2 (32->32) ----
    gemm_tile<32, 32, 8, false, true><<<cdiv(N, 64), 256, 0, stream>>>(
        bufA, lw2, lb2, nullptr, nullptr, out, N);
}

// Round 7
// 1217.364 us; speedup vs baseline: 2.2413x; 1.3241x over previous
//
#include <hip/hip_runtime.h>
#include <math.h>

#define N_NODES 100000
#define LN_EPS 1e-5f

// ---------------- small utility kernels ----------------
__global__ void zero_int(int* __restrict__ p, int n) {
    int i = blockIdx.x * blockDim.x + threadIdx.x;
    if (i < n) p[i] = 0;
}

__global__ void set_int(int* __restrict__ p, int v) {
    if (threadIdx.x == 0 && blockIdx.x == 0) *p = v;
}

__global__ void hist_dst(const int* __restrict__ dst, int* __restrict__ deg, int E) {
    int e = blockIdx.x * blockDim.x + threadIdx.x;
    if (e < E) atomicAdd(&deg[dst[e]], 1);
}

__global__ void deg_to_dinv(const int* __restrict__ deg, float* __restrict__ dinv, int n) {
    int i = blockIdx.x * blockDim.x + threadIdx.x;
    if (i < n) dinv[i] = rsqrtf((float)deg[i] + 1.f);
}

// exclusive scan, 256 elems/block
__global__ void scan_block(const int* __restrict__ in, int* __restrict__ out,
                           int* __restrict__ bsums, int n) {
    __shared__ int s[256];
    int i = blockIdx.x * 256 + threadIdx.x;
    int v = (i < n) ? in[i] : 0;
    s[threadIdx.x] = v;
    __syncthreads();
    for (int off = 1; off < 256; off <<= 1) {
        int t = ((int)threadIdx.x >= off) ? s[threadIdx.x - off] : 0;
        __syncthreads();
        s[threadIdx.x] += t;
        __syncthreads();
    }
    if (i < n) out[i] = s[threadIdx.x] - v;  // exclusive
    if (threadIdx.x == 255) bsums[blockIdx.x] = s[255];
}

__global__ void scan_sums(int* __restrict__ bsums, int nb) {
    if (threadIdx.x == 0 && blockIdx.x == 0) {
        int acc = 0;
        for (int i = 0; i < nb; ++i) { int t = bsums[i]; bsums[i] = acc; acc += t; }
    }
}

__global__ void scan_add(int* __restrict__ out, const int* __restrict__ bsums, int n) {
    int i = blockIdx.x * 256 + threadIdx.x;
    if (i < n) out[i] += bsums[blockIdx.x];
}

__global__ void fill_csr(const int* __restrict__ src, const int* __restrict__ dst,
                         const int* __restrict__ offsets, int* __restrict__ cursor,
                         int* __restrict__ csr_src, int E) {
    int e = blockIdx.x * blockDim.x + threadIdx.x;
    if (e < E) {
        int d = dst[e];
        int pos = offsets[d] + atomicAdd(&cursor[d], 1);
        csr_src[pos] = src[e];
    }
}

// ---------------- LDS-staged wave-cooperative gemm (+bias+LN+ELU) ----------------
// k4 loop MUST stay rolled (unroll 1): full unroll hoists 16 iters of LDS wf
// reads into registers -> 256 VGPRs -> GB-scale scratch spill (R4/R6 evidence).
template <int IN_C, int OUT_C, int NPW, bool LN, bool BIAS>
__launch_bounds__(256)
__global__ void gemm_tile(const float* __restrict__ X, const float* __restrict__ W,
                          const float* __restrict__ bias, const float* __restrict__ gamma,
                          const float* __restrict__ beta, float* __restrict__ Y, int n) {
    constexpr int LPN = (OUT_C < 64) ? OUT_C : 64;  // lanes per node-group
    constexpr int G   = 64 / LPN;                   // node groups per wave
    constexpr int JPL = (OUT_C + 63) / 64;          // cols per lane
    constexpr int NW  = 4;                          // waves per block
    constexpr int NPWG = NPW * G;                   // nodes per wave
    constexpr int C4  = IN_C / 4;

    __shared__ float sW[IN_C * OUT_C];
    __shared__ float4 sX[NW][NPWG * C4];

    for (int i = threadIdx.x; i < IN_C * OUT_C; i += 256) sW[i] = W[i];

    int wv = threadIdx.x >> 6, lane = threadIdx.x & 63;
    int g = lane / LPN;
    int col = lane % LPN;
    int nb = (blockIdx.x * NW + wv) * NPWG;  // wave's first node

    // stage x rows [nb, nb+NPWG) -- coalesced float4
    const float4* X4 = (const float4*)X;
#pragma unroll
    for (int i = 0; i < NPWG * C4 / 64; ++i) {
        int idx = i * 64 + lane;
        int row = idx / C4, c4 = idx % C4;
        int node = nb + row;
        node = (node < n) ? node : (n - 1);
        sX[wv][idx] = X4[(size_t)node * C4 + c4];
    }
    __syncthreads();  // sW ready (sX is wave-private)

    float acc[NPW][JPL];
#pragma unroll
    for (int m = 0; m < NPW; ++m)
#pragma unroll
        for (int jj = 0; jj < JPL; ++jj) acc[m][jj] = 0.f;

#pragma unroll 1
    for (int k4 = 0; k4 < C4; ++k4) {
        float wf[4][JPL];
#pragma unroll
        for (int kk = 0; kk < 4; ++kk)
#pragma unroll
            for (int jj = 0; jj < JPL; ++jj)
                wf[kk][jj] = sW[(k4 * 4 + kk) * OUT_C + col + jj * 64];
#pragma unroll 4
        for (int m = 0; m < NPW; ++m) {
            float4 xv = sX[wv][(g * NPW + m) * C4 + k4];  // broadcast within group
#pragma unroll
            for (int kk = 0; kk < 4; ++kk) {
                float xs = (kk == 0) ? xv.x : (kk == 1) ? xv.y : (kk == 2) ? xv.z : xv.w;
#pragma unroll
                for (int jj = 0; jj < JPL; ++jj) acc[m][jj] += xs * wf[kk][jj];
            }
        }
    }

    // epilogue
    float bj[JPL], gj[JPL], btj[JPL];
#pragma unroll
    for (int jj = 0; jj < JPL; ++jj) {
        int c = col + jj * 64;
        bj[jj]  = BIAS ? bias[c] : 0.f;
        gj[jj]  = LN ? gamma[c] : 1.f;
        btj[jj] = LN ? beta[c] : 0.f;
    }
#pragma unroll
    for (int m = 0; m < NPW; ++m) {
        int node = nb + g * NPW + m;
        if (LN) {
            float v[JPL];
            float s = 0.f, sq = 0.f;
#pragma unroll
            for (int jj = 0; jj < JPL; ++jj) {
                v[jj] = acc[m][jj] + bj[jj];
                s += v[jj];
                sq += v[jj] * v[jj];
            }
#pragma unroll
            for (int off = LPN / 2; off > 0; off >>= 1) {
                s += __shfl_xor(s, off, 64);
                sq += __shfl_xor(sq, off, 64);
            }
            float mu = s / OUT_C;
            float var = sq / OUT_C - mu * mu;
            float rs = rsqrtf(var + LN_EPS);
            if (node < n) {
#pragma unroll
                for (int jj = 0; jj < JPL; ++jj) {
                    float y = (v[jj] - mu) * rs * gj[jj] + btj[jj];
                    Y[(size_t)node * OUT_C + col + jj * 64] = y > 0.f ? y : expm1f(y);
                }
            }
        } else if (node < n) {
#pragma unroll
            for (int jj = 0; jj < JPL; ++jj)
                Y[(size_t)node * OUT_C + col + jj * 64] = acc[m][jj] + bj[jj];
        }
    }
}

// ---------------- fused gather (+ self loop) [+ bias + LN + ELU] ----------------
template <bool LN>
__global__ void gather64(const float* __restrict__ xw, const int* __restrict__ offsets,
                         const int* __restrict__ csr_src, const float* __restrict__ dinv,
                         const float* __restrict__ bias, const float* __restrict__ gamma,
                         const float* __restrict__ beta, float* __restrict__ out, int n) {
    int wave = threadIdx.x >> 6;
    int lane = threadIdx.x & 63;
    int node = blockIdx.x * (blockDim.x >> 6) + wave;
    if (node >= n) return;
    int beg = offsets[node], end = offsets[node + 1];

    float acc = 0.f;
    for (int base = beg; base < end; base += 64) {
        int m = min(64, end - base);
        int myS = (lane < m) ? csr_src[base + lane] : 0;
        float myN = (lane < m) ? dinv[myS] : 0.f;
        int j = 0;
        for (; j + 4 <= m; j += 4) {
            int s0 = __shfl(myS, j, 64), s1 = __shfl(myS, j + 1, 64);
            int s2 = __shfl(myS, j + 2, 64), s3 = __shfl(myS, j + 3, 64);
            float n0 = __shfl(myN, j, 64), n1 = __shfl(myN, j + 1, 64);
            float n2 = __shfl(myN, j + 2, 64), n3 = __shfl(myN, j + 3, 64);
            float r0 = xw[(size_t)s0 * 64 + lane];
            float r1 = xw[(size_t)s1 * 64 + lane];
            float r2 = xw[(size_t)s2 * 64 + lane];
            float r3 = xw[(size_t)s3 * 64 + lane];
            acc += r0 * n0;
            acc += r1 * n1;
            acc += r2 * n2;
            acc += r3 * n3;
        }
        for (; j < m; ++j) {
            int s = __shfl(myS, j, 64);
            float nm = __shfl(myN, j, 64);
            acc += xw[(size_t)s * 64 + lane] * nm;
        }
    }

    float dd = dinv[node];
    float y = acc * dd + xw[(size_t)node * 64 + lane] * dd * dd;
    if (!LN) {
        out[(size_t)node * 64 + lane] = y;
        return;
    }
    y += bias[lane];
    float s = y, sq = y * y;
#pragma unroll
    for (int off = 32; off > 0; off >>= 1) {
        s += __shfl_xor(s, off, 64);
        sq += __shfl_xor(sq, off, 64);
    }
    float mu = s / 64.f;
    float var = sq / 64.f - mu * mu;
    float rs = rsqrtf(var + LN_EPS);
    float z = (y - mu) * rs * gamma[lane] + beta[lane];
    out[(size_t)node * 64 + lane] = z > 0.f ? z : expm1f(z);
}

extern "C" void kernel_launch(void* const* d_in, const int* in_sizes, int n_in,
                              void* d_out, int out_size, void* d_ws, size_t ws_size,
                              hipStream_t stream) {
    const float* x  = (const float*)d_in[0];
    const int* ei   = (const int*)d_in[1];
    const float* W1 = (const float*)d_in[2];
    const float* b1 = (const float*)d_in[3];
    const float* g1 = (const float*)d_in[4];
    const float* be1= (const float*)d_in[5];
    const float* W2 = (const float*)d_in[6];
    const float* b2 = (const float*)d_in[7];
    const float* g2 = (const float*)d_in[8];
    const float* be2= (const float*)d_in[9];
    const float* W3 = (const float*)d_in[10];
    const float* b3 = (const float*)d_in[11];
    const float* g3 = (const float*)d_in[12];
    const float* be3= (const float*)d_in[13];
    const float* lw1= (const float*)d_in[14];
    const float* lb1= (const float*)d_in[15];
    const float* g4 = (const float*)d_in[16];
    const float* be4= (const float*)d_in[17];
    const float* lw2= (const float*)d_in[18];
    const float* lb2= (const float*)d_in[19];
    float* out = (float*)d_out;

    const int E = in_sizes[1] / 2;
    const int* src = ei;
    const int* dst = ei + E;
    const int N = N_NODES;

    // workspace layout
    float* bufA    = (float*)d_ws;                    // N*128
    float* bufB    = bufA + (size_t)N * 128;          // N*128
    float* dinv    = bufB + (size_t)N * 128;          // N
    int*   deg     = (int*)(dinv + N);                // N
    int*   offsets = deg + N;                         // N+1
    int*   cursor  = offsets + N + 1;                 // N
    int*   csr     = cursor + N;                      // E
    int*   bsums   = csr + E;                         // ceil(N/256)

    auto cdiv = [](long long a, long long b) { return (int)((a + b - 1) / b); };
    const int NB = cdiv(N, 256);

    // ---- build CSR (dst-sorted) + dinv ----
    zero_int<<<NB, 256, 0, stream>>>(deg, N);
    zero_int<<<NB, 256, 0, stream>>>(cursor, N);
    hist_dst<<<cdiv(E, 256), 256, 0, stream>>>(dst, deg, E);
    scan_block<<<NB, 256, 0, stream>>>(deg, offsets, bsums, N);
    scan_sums<<<1, 64, 0, stream>>>(bsums, NB);
    scan_add<<<NB, 256, 0, stream>>>(offsets, bsums, N);
    set_int<<<1, 64, 0, stream>>>(offsets + N, E);
    fill_csr<<<cdiv(E, 256), 256, 0, stream>>>(src, dst, offsets, cursor, csr, E);
    deg_to_dinv<<<NB, 256, 0, stream>>>(deg, dinv, N);

    // ---- Layer 1: xw1 = x @ W1 (128->64); h1 = LN_ELU(gather + b1) ----
    gemm_tile<128, 64, 8, false, false><<<cdiv(N, 32), 256, 0, stream>>>(
        x, W1, nullptr, nullptr, nullptr, bufA, N);
    gather64<true><<<cdiv(N, 4), 256, 0, stream>>>(bufA, offsets, csr, dinv, b1, g1, be1, bufB, N);

    // ---- Layer 2 (aggregate-first): a2 = gather(h1); h2 = LN_ELU(a2 @ W2 + b2) ----
    gather64<false><<<cdiv(N, 4), 256, 0, stream>>>(bufB, offsets, csr, dinv, nullptr, nullptr, nullptr, bufA, N);
    gemm_tile<64, 128, 8, true, true><<<cdiv(N, 32), 256, 0, stream>>>(
        bufA, W2, b2, g2, be2, bufB, N);

    // ---- Layer 3: xw3 = h2 @ W3 (128->64); h3 = LN_ELU(gather + b3) ----
    gemm_tile<128, 64, 8, false, false><<<cdiv(N, 32), 256, 0, stream>>>(
        bufB, W3, nullptr, nullptr, nullptr, bufA, N);
    gather64<true><<<cdiv(N, 4), 256, 0, stream>>>(bufA, offsets, csr, dinv, b3, g3, be3, bufB, N);

    // ---- lin1: t = LN_ELU(h3 @ lw1 + lb1) (64->32) ----
    gemm_tile<64, 32, 8, true, true><<<cdiv(N, 64), 256, 0, stream>>>(
        bufB, lw1, lb1, g4, be4, bufA, N);

    // ---- lin2: out = t @ lw2 + lb2 (32->32) ----
    gemm_tile<32, 32, 8, false, true><<<cdiv(N, 64), 256, 0, stream>>>(
        bufA, lw2, lb2, nullptr, nullptr, out, N);
}

// Round 8
// 616.146 us; speedup vs baseline: 4.4282x; 1.9758x over previous
//
#include <hip/hip_runtime.h>
#include <math.h>

#define N_NODES 100000
#define LN_EPS 1e-5f

typedef __attribute__((ext_vector_type(8))) short bf16x8;
typedef __attribute__((ext_vector_type(4))) float f32x4;

__device__ __forceinline__ unsigned short f2bf(float f) {
    unsigned int u = __float_as_uint(f);
    return (unsigned short)((u + 0x7FFFu + ((u >> 16) & 1u)) >> 16);
}

// ---------------- small utility kernels ----------------
__global__ void zero_int(int* __restrict__ p, int n) {
    int i = blockIdx.x * blockDim.x + threadIdx.x;
    if (i < n) p[i] = 0;
}

__global__ void set_int(int* __restrict__ p, int v) {
    if (threadIdx.x == 0 && blockIdx.x == 0) *p = v;
}

__global__ void hist_dst(const int* __restrict__ dst, int* __restrict__ deg, int E) {
    int e = blockIdx.x * blockDim.x + threadIdx.x;
    if (e < E) atomicAdd(&deg[dst[e]], 1);
}

__global__ void deg_to_dinv(const int* __restrict__ deg, float* __restrict__ dinv, int n) {
    int i = blockIdx.x * blockDim.x + threadIdx.x;
    if (i < n) dinv[i] = rsqrtf((float)deg[i] + 1.f);
}

// exclusive scan, 256 elems/block
__global__ void scan_block(const int* __restrict__ in, int* __restrict__ out,
                           int* __restrict__ bsums, int n) {
    __shared__ int s[256];
    int i = blockIdx.x * 256 + threadIdx.x;
    int v = (i < n) ? in[i] : 0;
    s[threadIdx.x] = v;
    __syncthreads();
    for (int off = 1; off < 256; off <<= 1) {
        int t = ((int)threadIdx.x >= off) ? s[threadIdx.x - off] : 0;
        __syncthreads();
        s[threadIdx.x] += t;
        __syncthreads();
    }
    if (i < n) out[i] = s[threadIdx.x] - v;  // exclusive
    if (threadIdx.x == 255) bsums[blockIdx.x] = s[255];
}

__global__ void scan_sums(int* __restrict__ bsums, int nb) {
    if (threadIdx.x == 0 && blockIdx.x == 0) {
        int acc = 0;
        for (int i = 0; i < nb; ++i) { int t = bsums[i]; bsums[i] = acc; acc += t; }
    }
}

__global__ void scan_add(int* __restrict__ out, const int* __restrict__ bsums, int n) {
    int i = blockIdx.x * 256 + threadIdx.x;
    if (i < n) out[i] += bsums[blockIdx.x];
}

__global__ void fill_csr(const int* __restrict__ src, const int* __restrict__ dst,
                         const int* __restrict__ offsets, int* __restrict__ cursor,
                         int* __restrict__ csr_src, int E) {
    int e = blockIdx.x * blockDim.x + threadIdx.x;
    if (e < E) {
        int d = dst[e];
        int pos = offsets[d] + atomicAdd(&cursor[d], 1);
        csr_src[pos] = src[e];
    }
}

// ---------------- MFMA bf16 gemm: Y = X[n,K] @ W[K,OUT] (+bias, +LN+ELU) ----------------
// 4 waves/block; wave w owns 16-row M-tile. A frags converted fp32->bf16 from
// global (lane: row=lane&15, k=quad*8+j). W^T staged bf16 in LDS (+8 pad: 2-way
// bank = free). C/D: col=lane&15, row=quad*4+reg (m89-verified). LN reduced
// across the 16 lanes of each quad via shfl_xor 1/2/4/8.
template <int K, int OUT, bool LN, bool BIAS>
__launch_bounds__(256)
__global__ void mfma_gemm(const float* __restrict__ X, const float* __restrict__ W,
                          const float* __restrict__ bias, const float* __restrict__ gamma,
                          const float* __restrict__ beta, float* __restrict__ Y, int n) {
    constexpr int T  = OUT / 16;   // 16-col output tiles
    constexpr int KP = K + 8;      // padded LDS row (bf16 elems)

    __shared__ __align__(16) unsigned short sWT[OUT * KP];  // W^T as [out][k] bf16
    for (int i = threadIdx.x; i < K * OUT; i += 256) {
        int k = i / OUT, o = i - k * OUT;
        sWT[o * KP + k] = f2bf(W[i]);
    }
    __syncthreads();

    int wv = threadIdx.x >> 6, lane = threadIdx.x & 63;
    int quad = lane >> 4, l16 = lane & 15;
    int m0 = (blockIdx.x * 4 + wv) * 16;
    int rowc = min(m0 + l16, n - 1);

    f32x4 acc[T];
#pragma unroll
    for (int t = 0; t < T; ++t) acc[t] = (f32x4){0.f, 0.f, 0.f, 0.f};

    const float4* X4 = (const float4*)X;
#pragma unroll
    for (int s = 0; s < K / 32; ++s) {
        int koff = s * 32 + quad * 8;
        size_t base = ((size_t)rowc * K + koff) >> 2;
        float4 a0 = X4[base];
        float4 a1 = X4[base + 1];
        bf16x8 af;
        af[0] = (short)f2bf(a0.x); af[1] = (short)f2bf(a0.y);
        af[2] = (short)f2bf(a0.z); af[3] = (short)f2bf(a0.w);
        af[4] = (short)f2bf(a1.x); af[5] = (short)f2bf(a1.y);
        af[6] = (short)f2bf(a1.z); af[7] = (short)f2bf(a1.w);
#pragma unroll
        for (int t = 0; t < T; ++t) {
            const bf16x8 bfrag = *(const bf16x8*)&sWT[(t * 16 + l16) * KP + koff];
            acc[t] = __builtin_amdgcn_mfma_f32_16x16x32_bf16(af, bfrag, acc[t], 0, 0, 0);
        }
    }

    float bj[T], gj[T], btj[T];
#pragma unroll
    for (int t = 0; t < T; ++t) {
        int c = t * 16 + l16;
        bj[t]  = BIAS ? bias[c] : 0.f;
        gj[t]  = LN ? gamma[c] : 1.f;
        btj[t] = LN ? beta[c] : 0.f;
    }

    if (LN) {
        float s[4] = {0.f, 0.f, 0.f, 0.f}, sq[4] = {0.f, 0.f, 0.f, 0.f};
#pragma unroll
        for (int t = 0; t < T; ++t)
#pragma unroll
            for (int r = 0; r < 4; ++r) {
                float v = acc[t][r] + bj[t];
                s[r] += v;
                sq[r] += v * v;
            }
#pragma unroll
        for (int off = 1; off < 16; off <<= 1)
#pragma unroll
            for (int r = 0; r < 4; ++r) {
                s[r] += __shfl_xor(s[r], off, 64);
                sq[r] += __shfl_xor(sq[r], off, 64);
            }
        float mu[4], rs[4];
#pragma unroll
        for (int r = 0; r < 4; ++r) {
            mu[r] = s[r] / OUT;
            float var = sq[r] / OUT - mu[r] * mu[r];
            rs[r] = rsqrtf(var + LN_EPS);
        }
#pragma unroll
        for (int r = 0; r < 4; ++r) {
            int rowg = m0 + quad * 4 + r;
            if (rowg < n) {
#pragma unroll
                for (int t = 0; t < T; ++t) {
                    float y = (acc[t][r] + bj[t] - mu[r]) * rs[r] * gj[t] + btj[t];
                    y = y > 0.f ? y : expm1f(y);
                    Y[(size_t)rowg * OUT + t * 16 + l16] = y;
                }
            }
        }
    } else {
#pragma unroll
        for (int r = 0; r < 4; ++r) {
            int rowg = m0 + quad * 4 + r;
            if (rowg < n) {
#pragma unroll
                for (int t = 0; t < T; ++t)
                    Y[(size_t)rowg * OUT + t * 16 + l16] = acc[t][r] + bj[t];
            }
        }
    }
}

// ---------------- fused gather (+ self loop) [+ bias + LN + ELU] ----------------
template <bool LN>
__global__ void gather64(const float* __restrict__ xw, const int* __restrict__ offsets,
                         const int* __restrict__ csr_src, const float* __restrict__ dinv,
                         const float* __restrict__ bias, const float* __restrict__ gamma,
                         const float* __restrict__ beta, float* __restrict__ out, int n) {
    int wave = threadIdx.x >> 6;
    int lane = threadIdx.x & 63;
    int node = blockIdx.x * (blockDim.x >> 6) + wave;
    if (node >= n) return;
    int beg = offsets[node], end = offsets[node + 1];

    float acc = 0.f;
    for (int base = beg; base < end; base += 64) {
        int m = min(64, end - base);
        int myS = (lane < m) ? csr_src[base + lane] : 0;
        float myN = (lane < m) ? dinv[myS] : 0.f;
        int j = 0;
        for (; j + 4 <= m; j += 4) {
            int s0 = __shfl(myS, j, 64), s1 = __shfl(myS, j + 1, 64);
            int s2 = __shfl(myS, j + 2, 64), s3 = __shfl(myS, j + 3, 64);
            float n0 = __shfl(myN, j, 64), n1 = __shfl(myN, j + 1, 64);
            float n2 = __shfl(myN, j + 2, 64), n3 = __shfl(myN, j + 3, 64);
            float r0 = xw[(size_t)s0 * 64 + lane];
            float r1 = xw[(size_t)s1 * 64 + lane];
            float r2 = xw[(size_t)s2 * 64 + lane];
            float r3 = xw[(size_t)s3 * 64 + lane];
            acc += r0 * n0;
            acc += r1 * n1;
            acc += r2 * n2;
            acc += r3 * n3;
        }
        for (; j < m; ++j) {
            int s = __shfl(myS, j, 64);
            float nm = __shfl(myN, j, 64);
            acc += xw[(size_t)s * 64 + lane] * nm;
        }
    }

    float dd = dinv[node];
    float y = acc * dd + xw[(size_t)node * 64 + lane] * dd * dd;
    if (!LN) {
        out[(size_t)node * 64 + lane] = y;
        return;
    }
    y += bias[lane];
    float s = y, sq = y * y;
#pragma unroll
    for (int off = 32; off > 0; off >>= 1) {
        s += __shfl_xor(s, off, 64);
        sq += __shfl_xor(sq, off, 64);
    }
    float mu = s / 64.f;
    float var = sq / 64.f - mu * mu;
    float rs = rsqrtf(var + LN_EPS);
    float z = (y - mu) * rs * gamma[lane] + beta[lane];
    out[(size_t)node * 64 + lane] = z > 0.f ? z : expm1f(z);
}

extern "C" void kernel_launch(void* const* d_in, const int* in_sizes, int n_in,
                              void* d_out, int out_size, void* d_ws, size_t ws_size,
                              hipStream_t stream) {
    const float* x  = (const float*)d_in[0];
    const int* ei   = (const int*)d_in[1];
    const float* W1 = (const float*)d_in[2];
    const float* b1 = (const float*)d_in[3];
    const float* g1 = (const float*)d_in[4];
    const float* be1= (const float*)d_in[5];
    const float* W2 = (const float*)d_in[6];
    const float* b2 = (const float*)d_in[7];
    const float* g2 = (const float*)d_in[8];
    const float* be2= (const float*)d_in[9];
    const float* W3 = (const float*)d_in[10];
    const float* b3 = (const float*)d_in[11];
    const float* g3 = (const float*)d_in[12];
    const float* be3= (const float*)d_in[13];
    const float* lw1= (const float*)d_in[14];
    const float* lb1= (const float*)d_in[15];
    const float* g4 = (const float*)d_in[16];
    const float* be4= (const float*)d_in[17];
    const float* lw2= (const float*)d_in[18];
    const float* lb2= (const float*)d_in[19];
    float* out = (float*)d_out;

    const int E = in_sizes[1] / 2;
    const int* src = ei;
    const int* dst = ei + E;
    const int N = N_NODES;

    // workspace layout
    float* bufA    = (float*)d_ws;                    // N*128
    float* bufB    = bufA + (size_t)N * 128;          // N*128
    float* dinv    = bufB + (size_t)N * 128;          // N
    int*   deg     = (int*)(dinv + N);                // N
    int*   offsets = deg + N;                         // N+1
    int*   cursor  = offsets + N + 1;                 // N
    int*   csr     = cursor + N;                      // E
    int*   bsums   = csr + E;                         // ceil(N/256)

    auto cdiv = [](long long a, long long b) { return (int)((a + b - 1) / b); };
    const int NB = cdiv(N, 256);
    const int GB = cdiv(N, 64);  // mfma gemm grid (64 rows/block)

    // ---- build CSR (dst-sorted) + dinv ----
    zero_int<<<NB, 256, 0, stream>>>(deg, N);
    zero_int<<<NB, 256, 0, stream>>>(cursor, N);
    hist_dst<<<cdiv(E, 256), 256, 0, stream>>>(dst, deg, E);
    scan_block<<<NB, 256, 0, stream>>>(deg, offsets, bsums, N);
    scan_sums<<<1, 64, 0, stream>>>(bsums, NB);
    scan_add<<<NB, 256, 0, stream>>>(offsets, bsums, N);
    set_int<<<1, 64, 0, stream>>>(offsets + N, E);
    fill_csr<<<cdiv(E, 256), 256, 0, stream>>>(src, dst, offsets, cursor, csr, E);
    deg_to_dinv<<<NB, 256, 0, stream>>>(deg, dinv, N);

    // ---- Layer 1: xw1 = x @ W1 (128->64); h1 = LN_ELU(gather + b1) ----
    mfma_gemm<128, 64, false, false><<<GB, 256, 0, stream>>>(
        x, W1, nullptr, nullptr, nullptr, bufA, N);
    gather64<true><<<cdiv(N, 4), 256, 0, stream>>>(bufA, offsets, csr, dinv, b1, g1, be1, bufB, N);

    // ---- Layer 2 (aggregate-first): a2 = gather(h1); h2 = LN_ELU(a2 @ W2 + b2) ----
    gather64<false><<<cdiv(N, 4), 256, 0, stream>>>(bufB, offsets, csr, dinv, nullptr, nullptr, nullptr, bufA, N);
    mfma_gemm<64, 128, true, true><<<GB, 256, 0, stream>>>(
        bufA, W2, b2, g2, be2, bufB, N);

    // ---- Layer 3: xw3 = h2 @ W3 (128->64); h3 = LN_ELU(gather + b3) ----
    mfma_gemm<128, 64, false, false><<<GB, 256, 0, stream>>>(
        bufB, W3, nullptr, nullptr, nullptr, bufA, N);
    gather64<true><<<cdiv(N, 4), 256, 0, stream>>>(bufA, offsets, csr, dinv, b3, g3, be3, bufB, N);

    // ---- lin1: t = LN_ELU(h3 @ lw1 + lb1) (64->32) ----
    mfma_gemm<64, 32, true, true><<<GB, 256, 0, stream>>>(
        bufB, lw1, lb1, g4, be4, bufA, N);

    // ---- lin2: out = t @ lw2 + lb2 (32->32) ----
    mfma_gemm<32, 32, false, true><<<GB, 256, 0, stream>>>(
        bufA, lw2, lb2, nullptr, nullptr, out, N);
}

// Round 9
// 591.018 us; speedup vs baseline: 4.6165x; 1.0425x over previous
//
#include <hip/hip_runtime.h>
#include <math.h>

#define N_NODES 100000
#define LN_EPS 1e-5f

typedef __attribute__((ext_vector_type(8))) short bf16x8;
typedef __attribute__((ext_vector_type(4))) float f32x4;

__device__ __forceinline__ unsigned short f2bf(float f) {
    unsigned int u = __float_as_uint(f);
    return (unsigned short)((u + 0x7FFFu + ((u >> 16) & 1u)) >> 16);
}
__device__ __forceinline__ float bf2f(unsigned short u) {
    return __uint_as_float(((unsigned int)u) << 16);
}

// ---------------- small utility kernels ----------------
__global__ void zero_int(int* __restrict__ p, int n) {
    int i = blockIdx.x * blockDim.x + threadIdx.x;
    if (i < n) p[i] = 0;
}

__global__ void set_int(int* __restrict__ p, int v) {
    if (threadIdx.x == 0 && blockIdx.x == 0) *p = v;
}

__global__ void hist_dst(const int* __restrict__ dst, int* __restrict__ deg, int E) {
    int e = blockIdx.x * blockDim.x + threadIdx.x;
    if (e < E) atomicAdd(&deg[dst[e]], 1);
}

__global__ void deg_to_dinv(const int* __restrict__ deg, float* __restrict__ dinv, int n) {
    int i = blockIdx.x * blockDim.x + threadIdx.x;
    if (i < n) dinv[i] = rsqrtf((float)deg[i] + 1.f);
}

// exclusive scan, 256 elems/block
__global__ void scan_block(const int* __restrict__ in, int* __restrict__ out,
                           int* __restrict__ bsums, int n) {
    __shared__ int s[256];
    int i = blockIdx.x * 256 + threadIdx.x;
    int v = (i < n) ? in[i] : 0;
    s[threadIdx.x] = v;
    __syncthreads();
    for (int off = 1; off < 256; off <<= 1) {
        int t = ((int)threadIdx.x >= off) ? s[threadIdx.x - off] : 0;
        __syncthreads();
        s[threadIdx.x] += t;
        __syncthreads();
    }
    if (i < n) out[i] = s[threadIdx.x] - v;  // exclusive
    if (threadIdx.x == 255) bsums[blockIdx.x] = s[255];
}

__global__ void scan_sums(int* __restrict__ bsums, int nb) {
    if (threadIdx.x == 0 && blockIdx.x == 0) {
        int acc = 0;
        for (int i = 0; i < nb; ++i) { int t = bsums[i]; bsums[i] = acc; acc += t; }
    }
}

// finalize offsets AND init cursor=offsets (fold the copy into this pass)
__global__ void scan_add_copy(int* __restrict__ out, int* __restrict__ cursor,
                              const int* __restrict__ bsums, int n) {
    int i = blockIdx.x * 256 + threadIdx.x;
    if (i < n) {
        int v = out[i] + bsums[blockIdx.x];
        out[i] = v;
        cursor[i] = v;
    }
}

__global__ void fill_csr(const int* __restrict__ src, const int* __restrict__ dst,
                         int* __restrict__ cursor, int* __restrict__ csr_src, int E) {
    int e = blockIdx.x * blockDim.x + threadIdx.x;
    if (e < E) {
        int pos = atomicAdd(&cursor[dst[e]], 1);
        csr_src[pos] = src[e];
    }
}

// ---------------- MFMA bf16 gemm: Y = X[n,K] @ W[K,OUT] (+bias, +LN+ELU) ----------------
// 4 waves/block; wave owns 16-row M-tile. A frags: bf16 direct (AF32=false) or
// fp32->bf16 convert (AF32=true, layer-1 input only). W^T staged bf16 in LDS
// (+8 pad). C/D: col=lane&15, row=quad*4+reg. LN via 16-lane shfl_xor reduce.
template <int K, int OUT, bool LN, bool BIAS, bool AF32, bool OF32>
__launch_bounds__(256)
__global__ void mfma_gemm(const void* __restrict__ Xv, const float* __restrict__ W,
                          const float* __restrict__ bias, const float* __restrict__ gamma,
                          const float* __restrict__ beta, void* __restrict__ Yv, int n) {
    constexpr int T  = OUT / 16;   // 16-col output tiles
    constexpr int KP = K + 8;      // padded LDS row (bf16 elems)

    __shared__ __align__(16) unsigned short sWT[OUT * KP];  // W^T as [out][k] bf16
    for (int i = threadIdx.x; i < K * OUT; i += 256) {
        int k = i / OUT, o = i - k * OUT;
        sWT[o * KP + k] = f2bf(W[i]);
    }
    __syncthreads();

    int wv = threadIdx.x >> 6, lane = threadIdx.x & 63;
    int quad = lane >> 4, l16 = lane & 15;
    int m0 = (blockIdx.x * 4 + wv) * 16;
    int rowc = min(m0 + l16, n - 1);

    f32x4 acc[T];
#pragma unroll
    for (int t = 0; t < T; ++t) acc[t] = (f32x4){0.f, 0.f, 0.f, 0.f};

#pragma unroll
    for (int s = 0; s < K / 32; ++s) {
        int koff = s * 32 + quad * 8;
        bf16x8 af;
        if (AF32) {
            const float4* X4 = (const float4*)Xv;
            size_t base = ((size_t)rowc * K + koff) >> 2;
            float4 a0 = X4[base];
            float4 a1 = X4[base + 1];
            af[0] = (short)f2bf(a0.x); af[1] = (short)f2bf(a0.y);
            af[2] = (short)f2bf(a0.z); af[3] = (short)f2bf(a0.w);
            af[4] = (short)f2bf(a1.x); af[5] = (short)f2bf(a1.y);
            af[6] = (short)f2bf(a1.z); af[7] = (short)f2bf(a1.w);
        } else {
            const unsigned short* Xb = (const unsigned short*)Xv;
            af = *(const bf16x8*)(Xb + (size_t)rowc * K + koff);
        }
#pragma unroll
        for (int t = 0; t < T; ++t) {
            const bf16x8 bfrag = *(const bf16x8*)&sWT[(t * 16 + l16) * KP + koff];
            acc[t] = __builtin_amdgcn_mfma_f32_16x16x32_bf16(af, bfrag, acc[t], 0, 0, 0);
        }
    }

    float bj[T], gj[T], btj[T];
#pragma unroll
    for (int t = 0; t < T; ++t) {
        int c = t * 16 + l16;
        bj[t]  = BIAS ? bias[c] : 0.f;
        gj[t]  = LN ? gamma[c] : 1.f;
        btj[t] = LN ? beta[c] : 0.f;
    }

    float* Yf = (float*)Yv;
    unsigned short* Yb = (unsigned short*)Yv;

    if (LN) {
        float s[4] = {0.f, 0.f, 0.f, 0.f}, sq[4] = {0.f, 0.f, 0.f, 0.f};
#pragma unroll
        for (int t = 0; t < T; ++t)
#pragma unroll
            for (int r = 0; r < 4; ++r) {
                float v = acc[t][r] + bj[t];
                s[r] += v;
                sq[r] += v * v;
            }
#pragma unroll
        for (int off = 1; off < 16; off <<= 1)
#pragma unroll
            for (int r = 0; r < 4; ++r) {
                s[r] += __shfl_xor(s[r], off, 64);
                sq[r] += __shfl_xor(sq[r], off, 64);
            }
        float mu[4], rs[4];
#pragma unroll
        for (int r = 0; r < 4; ++r) {
            mu[r] = s[r] / OUT;
            float var = sq[r] / OUT - mu[r] * mu[r];
            rs[r] = rsqrtf(var + LN_EPS);
        }
#pragma unroll
        for (int r = 0; r < 4; ++r) {
            int rowg = m0 + quad * 4 + r;
            if (rowg < n) {
#pragma unroll
                for (int t = 0; t < T; ++t) {
                    float y = (acc[t][r] + bj[t] - mu[r]) * rs[r] * gj[t] + btj[t];
                    y = y > 0.f ? y : expm1f(y);
                    size_t idx = (size_t)rowg * OUT + t * 16 + l16;
                    if (OF32) Yf[idx] = y; else Yb[idx] = f2bf(y);
                }
            }
        }
    } else {
#pragma unroll
        for (int r = 0; r < 4; ++r) {
            int rowg = m0 + quad * 4 + r;
            if (rowg < n) {
#pragma unroll
                for (int t = 0; t < T; ++t) {
                    float y = acc[t][r] + bj[t];
                    size_t idx = (size_t)rowg * OUT + t * 16 + l16;
                    if (OF32) Yf[idx] = y; else Yb[idx] = f2bf(y);
                }
            }
        }
    }
}

// ---------------- fused gather (+ self loop) [+ bias + LN + ELU], bf16 I/O ----------------
template <bool LN>
__global__ void gather64(const unsigned short* __restrict__ xw, const int* __restrict__ offsets,
                         const int* __restrict__ csr_src, const float* __restrict__ dinv,
                         const float* __restrict__ bias, const float* __restrict__ gamma,
                         const float* __restrict__ beta, unsigned short* __restrict__ out, int n) {
    int wave = threadIdx.x >> 6;
    int lane = threadIdx.x & 63;
    int node = blockIdx.x * (blockDim.x >> 6) + wave;
    if (node >= n) return;
    int beg = offsets[node], end = offsets[node + 1];

    float acc = 0.f;
    for (int base = beg; base < end; base += 64) {
        int m = min(64, end - base);
        int myS = (lane < m) ? csr_src[base + lane] : 0;
        float myN = (lane < m) ? dinv[myS] : 0.f;
        int j = 0;
        for (; j + 4 <= m; j += 4) {
            int s0 = __shfl(myS, j, 64), s1 = __shfl(myS, j + 1, 64);
            int s2 = __shfl(myS, j + 2, 64), s3 = __shfl(myS, j + 3, 64);
            float n0 = __shfl(myN, j, 64), n1 = __shfl(myN, j + 1, 64);
            float n2 = __shfl(myN, j + 2, 64), n3 = __shfl(myN, j + 3, 64);
            float r0 = bf2f(xw[(size_t)s0 * 64 + lane]);
            float r1 = bf2f(xw[(size_t)s1 * 64 + lane]);
            float r2 = bf2f(xw[(size_t)s2 * 64 + lane]);
            float r3 = bf2f(xw[(size_t)s3 * 64 + lane]);
            acc += r0 * n0;
            acc += r1 * n1;
            acc += r2 * n2;
            acc += r3 * n3;
        }
        for (; j < m; ++j) {
            int s = __shfl(myS, j, 64);
            float nm = __shfl(myN, j, 64);
            acc += bf2f(xw[(size_t)s * 64 + lane]) * nm;
        }
    }

    float dd = dinv[node];
    float y = acc * dd + bf2f(xw[(size_t)node * 64 + lane]) * dd * dd;
    if (!LN) {
        out[(size_t)node * 64 + lane] = f2bf(y);
        return;
    }
    y += bias[lane];
    float s = y, sq = y * y;
#pragma unroll
    for (int off = 32; off > 0; off >>= 1) {
        s += __shfl_xor(s, off, 64);
        sq += __shfl_xor(sq, off, 64);
    }
    float mu = s / 64.f;
    float var = sq / 64.f - mu * mu;
    float rs = rsqrtf(var + LN_EPS);
    float z = (y - mu) * rs * gamma[lane] + beta[lane];
    out[(size_t)node * 64 + lane] = f2bf(z > 0.f ? z : expm1f(z));
}

extern "C" void kernel_launch(void* const* d_in, const int* in_sizes, int n_in,
                              void* d_out, int out_size, void* d_ws, size_t ws_size,
                              hipStream_t stream) {
    const float* x  = (const float*)d_in[0];
    const int* ei   = (const int*)d_in[1];
    const float* W1 = (const float*)d_in[2];
    const float* b1 = (const float*)d_in[3];
    const float* g1 = (const float*)d_in[4];
    const float* be1= (const float*)d_in[5];
    const float* W2 = (const float*)d_in[6];
    const float* b2 = (const float*)d_in[7];
    const float* g2 = (const float*)d_in[8];
    const float* be2= (const float*)d_in[9];
    const float* W3 = (const float*)d_in[10];
    const float* b3 = (const float*)d_in[11];
    const float* g3 = (const float*)d_in[12];
    const float* be3= (const float*)d_in[13];
    const float* lw1= (const float*)d_in[14];
    const float* lb1= (const float*)d_in[15];
    const float* g4 = (const float*)d_in[16];
    const float* be4= (const float*)d_in[17];
    const float* lw2= (const float*)d_in[18];
    const float* lb2= (const float*)d_in[19];
    float* out = (float*)d_out;

    const int E = in_sizes[1] / 2;
    const int* src = ei;
    const int* dst = ei + E;
    const int N = N_NODES;

    // workspace layout (intermediates in bf16)
    unsigned short* bufA = (unsigned short*)d_ws;       // N*128 bf16
    unsigned short* bufB = bufA + (size_t)N * 128;      // N*128 bf16
    float* dinv    = (float*)(bufB + (size_t)N * 128);  // N f32
    int*   deg     = (int*)(dinv + N);                  // N
    int*   offsets = deg + N;                           // N+1
    int*   cursor  = offsets + N + 1;                   // N
    int*   csr     = cursor + N;                        // E
    int*   bsums   = csr + E;                           // ceil(N/256)

    auto cdiv = [](long long a, long long b) { return (int)((a + b - 1) / b); };
    const int NB = cdiv(N, 256);
    const int GB = cdiv(N, 64);  // mfma gemm grid (64 rows/block)

    // ---- build CSR (dst-sorted) + dinv ----
    zero_int<<<NB, 256, 0, stream>>>(deg, N);
    hist_dst<<<cdiv(E, 256), 256, 0, stream>>>(dst, deg, E);
    scan_block<<<NB, 256, 0, stream>>>(deg, offsets, bsums, N);
    scan_sums<<<1, 64, 0, stream>>>(bsums, NB);
    scan_add_copy<<<NB, 256, 0, stream>>>(offsets, cursor, bsums, N);
    set_int<<<1, 64, 0, stream>>>(offsets + N, E);
    fill_csr<<<cdiv(E, 256), 256, 0, stream>>>(src, dst, cursor, csr, E);
    deg_to_dinv<<<NB, 256, 0, stream>>>(deg, dinv, N);

    // ---- Layer 1: xw1 = x @ W1 (128->64, fp32 in, bf16 out); h1 = LN_ELU(gather + b1) ----
    mfma_gemm<128, 64, false, false, true, false><<<GB, 256, 0, stream>>>(
        x, W1, nullptr, nullptr, nullptr, bufA, N);
    gather64<true><<<cdiv(N, 4), 256, 0, stream>>>(bufA, offsets, csr, dinv, b1, g1, be1, bufB, N);

    // ---- Layer 2 (aggregate-first): a2 = gather(h1); h2 = LN_ELU(a2 @ W2 + b2) ----
    gather64<false><<<cdiv(N, 4), 256, 0, stream>>>(bufB, offsets, csr, dinv, nullptr, nullptr, nullptr, bufA, N);
    mfma_gemm<64, 128, true, true, false, false><<<GB, 256, 0, stream>>>(
        bufA, W2, b2, g2, be2, bufB, N);

    // ---- Layer 3: xw3 = h2 @ W3 (128->64); h3 = LN_ELU(gather + b3) ----
    mfma_gemm<128, 64, false, false, false, false><<<GB, 256, 0, stream>>>(
        bufB, W3, nullptr, nullptr, nullptr, bufA, N);
    gather64<true><<<cdiv(N, 4), 256, 0, stream>>>(bufA, offsets, csr, dinv, b3, g3, be3, bufB, N);

    // ---- lin1: t = LN_ELU(h3 @ lw1 + lb1) (64->32) ----
    mfma_gemm<64, 32, true, true, false, false><<<GB, 256, 0, stream>>>(
        bufB, lw1, lb1, g4, be4, bufA, N);

    // ---- lin2: out = t @ lw2 + lb2 (32->32, fp32 out) ----
    mfma_gemm<32, 32, false, true, false, true><<<GB, 256, 0, stream>>>(
        bufA, lw2, lb2, nullptr, nullptr, out, N);
}

// Round 10
// 546.527 us; speedup vs baseline: 4.9923x; 1.0814x over previous
//
#include <hip/hip_runtime.h>
#include <math.h>

#define N_NODES 100000
#define LN_EPS 1e-5f

typedef __attribute__((ext_vector_type(8))) short bf16x8;
typedef __attribute__((ext_vector_type(4))) float f32x4;

__device__ __forceinline__ unsigned short f2bf(float f) {
    unsigned int u = __float_as_uint(f);
    return (unsigned short)((u + 0x7FFFu + ((u >> 16) & 1u)) >> 16);
}
__device__ __forceinline__ float bf2f(unsigned short u) {
    return __uint_as_float(((unsigned int)u) << 16);
}

// ---------------- small utility kernels ----------------
__global__ void zero_int(int* __restrict__ p, int n) {
    int i = blockIdx.x * blockDim.x + threadIdx.x;
    if (i < n) p[i] = 0;
}

__global__ void hist_dst(const int* __restrict__ dst, int* __restrict__ deg, int E) {
    int e = blockIdx.x * blockDim.x + threadIdx.x;
    if (e < E) atomicAdd(&deg[dst[e]], 1);
}

// exclusive scan (256/block) + fused dinv = rsqrt(deg+1)
__global__ void scan_block_dinv(const int* __restrict__ in, int* __restrict__ out,
                                int* __restrict__ bsums, float* __restrict__ dinv, int n) {
    __shared__ int s[256];
    int i = blockIdx.x * 256 + threadIdx.x;
    int v = (i < n) ? in[i] : 0;
    s[threadIdx.x] = v;
    __syncthreads();
    for (int off = 1; off < 256; off <<= 1) {
        int t = ((int)threadIdx.x >= off) ? s[threadIdx.x - off] : 0;
        __syncthreads();
        s[threadIdx.x] += t;
        __syncthreads();
    }
    if (i < n) {
        out[i] = s[threadIdx.x] - v;  // exclusive
        dinv[i] = rsqrtf((float)v + 1.f);
    }
    if (threadIdx.x == 255) bsums[blockIdx.x] = s[255];
}

// parallel exclusive scan of block sums (nb <= 512) + set offsets[N]=E
__global__ void scan_sums_p(int* __restrict__ bsums, int nb, int* __restrict__ off_end, int Ev) {
    __shared__ int s[512];
    int i = threadIdx.x;
    int v = (i < nb) ? bsums[i] : 0;
    s[i] = v;
    __syncthreads();
    for (int off = 1; off < 512; off <<= 1) {
        int t = (i >= off) ? s[i - off] : 0;
        __syncthreads();
        s[i] += t;
        __syncthreads();
    }
    if (i < nb) bsums[i] = s[i] - v;
    if (i == 0) *off_end = Ev;
}

// finalize offsets AND init cursor=offsets
__global__ void scan_add_copy(int* __restrict__ out, int* __restrict__ cursor,
                              const int* __restrict__ bsums, int n) {
    int i = blockIdx.x * 256 + threadIdx.x;
    if (i < n) {
        int v = out[i] + bsums[blockIdx.x];
        out[i] = v;
        cursor[i] = v;
    }
}

__global__ void fill_csr(const int* __restrict__ src, const int* __restrict__ dst,
                         int* __restrict__ cursor, int* __restrict__ csr_src, int E) {
    int e = blockIdx.x * blockDim.x + threadIdx.x;
    if (e < E) {
        int pos = atomicAdd(&cursor[dst[e]], 1);
        csr_src[pos] = src[e];
    }
}

// ---------------- MFMA bf16 gemm: Y = X[n,K] @ W[K,OUT] (+bias, +LN+ELU) ----------------
template <int K, int OUT, bool LN, bool BIAS, bool AF32, bool OF32>
__launch_bounds__(256)
__global__ void mfma_gemm(const void* __restrict__ Xv, const float* __restrict__ W,
                          const float* __restrict__ bias, const float* __restrict__ gamma,
                          const float* __restrict__ beta, void* __restrict__ Yv, int n) {
    constexpr int T  = OUT / 16;
    constexpr int KP = K + 8;

    __shared__ __align__(16) unsigned short sWT[OUT * KP];  // W^T bf16
    for (int i = threadIdx.x; i < K * OUT; i += 256) {
        int k = i / OUT, o = i - k * OUT;
        sWT[o * KP + k] = f2bf(W[i]);
    }
    __syncthreads();

    int wv = threadIdx.x >> 6, lane = threadIdx.x & 63;
    int quad = lane >> 4, l16 = lane & 15;
    int m0 = (blockIdx.x * 4 + wv) * 16;
    int rowc = min(m0 + l16, n - 1);

    f32x4 acc[T];
#pragma unroll
    for (int t = 0; t < T; ++t) acc[t] = (f32x4){0.f, 0.f, 0.f, 0.f};

#pragma unroll
    for (int s = 0; s < K / 32; ++s) {
        int koff = s * 32 + quad * 8;
        bf16x8 af;
        if (AF32) {
            const float4* X4 = (const float4*)Xv;
            size_t base = ((size_t)rowc * K + koff) >> 2;
            float4 a0 = X4[base];
            float4 a1 = X4[base + 1];
            af[0] = (short)f2bf(a0.x); af[1] = (short)f2bf(a0.y);
            af[2] = (short)f2bf(a0.z); af[3] = (short)f2bf(a0.w);
            af[4] = (short)f2bf(a1.x); af[5] = (short)f2bf(a1.y);
            af[6] = (short)f2bf(a1.z); af[7] = (short)f2bf(a1.w);
        } else {
            const unsigned short* Xb = (const unsigned short*)Xv;
            af = *(const bf16x8*)(Xb + (size_t)rowc * K + koff);
        }
#pragma unroll
        for (int t = 0; t < T; ++t) {
            const bf16x8 bfrag = *(const bf16x8*)&sWT[(t * 16 + l16) * KP + koff];
            acc[t] = __builtin_amdgcn_mfma_f32_16x16x32_bf16(af, bfrag, acc[t], 0, 0, 0);
        }
    }

    float bj[T], gj[T], btj[T];
#pragma unroll
    for (int t = 0; t < T; ++t) {
        int c = t * 16 + l16;
        bj[t]  = BIAS ? bias[c] : 0.f;
        gj[t]  = LN ? gamma[c] : 1.f;
        btj[t] = LN ? beta[c] : 0.f;
    }

    float* Yf = (float*)Yv;
    unsigned short* Yb = (unsigned short*)Yv;

    if (LN) {
        float s[4] = {0.f, 0.f, 0.f, 0.f}, sq[4] = {0.f, 0.f, 0.f, 0.f};
#pragma unroll
        for (int t = 0; t < T; ++t)
#pragma unroll
            for (int r = 0; r < 4; ++r) {
                float v = acc[t][r] + bj[t];
                s[r] += v;
                sq[r] += v * v;
            }
#pragma unroll
        for (int off = 1; off < 16; off <<= 1)
#pragma unroll
            for (int r = 0; r < 4; ++r) {
                s[r] += __shfl_xor(s[r], off, 64);
                sq[r] += __shfl_xor(sq[r], off, 64);
            }
        float mu[4], rs[4];
#pragma unroll
        for (int r = 0; r < 4; ++r) {
            mu[r] = s[r] / OUT;
            float var = sq[r] / OUT - mu[r] * mu[r];
            rs[r] = rsqrtf(var + LN_EPS);
        }
#pragma unroll
        for (int r = 0; r < 4; ++r) {
            int rowg = m0 + quad * 4 + r;
            if (rowg < n) {
#pragma unroll
                for (int t = 0; t < T; ++t) {
                    float y = (acc[t][r] + bj[t] - mu[r]) * rs[r] * gj[t] + btj[t];
                    y = y > 0.f ? y : expm1f(y);
                    size_t idx = (size_t)rowg * OUT + t * 16 + l16;
                    if (OF32) Yf[idx] = y; else Yb[idx] = f2bf(y);
                }
            }
        }
    } else {
#pragma unroll
        for (int r = 0; r < 4; ++r) {
            int rowg = m0 + quad * 4 + r;
            if (rowg < n) {
#pragma unroll
                for (int t = 0; t < T; ++t) {
                    float y = acc[t][r] + bj[t];
                    size_t idx = (size_t)rowg * OUT + t * 16 + l16;
                    if (OF32) Yf[idx] = y; else Yb[idx] = f2bf(y);
                }
            }
        }
    }
}

// ---------------- fused gather v2: 4 edges per wave-load (ushort4/lane) ----------------
// lane = quad(edge-in-group) x q16(col-group); one 8B load/lane covers
// 4 edges x 128B rows. Quad partial sums combined via shfl_xor 16/32.
template <bool LN>
__global__ void gather64(const unsigned short* __restrict__ xw, const int* __restrict__ offsets,
                         const int* __restrict__ csr_src, const float* __restrict__ dinv,
                         const float* __restrict__ bias, const float* __restrict__ gamma,
                         const float* __restrict__ beta, unsigned short* __restrict__ out, int n) {
    int wave = threadIdx.x >> 6;
    int lane = threadIdx.x & 63;
    int node = blockIdx.x * (blockDim.x >> 6) + wave;
    if (node >= n) return;
    int beg = offsets[node], end = offsets[node + 1];
    int quad = lane >> 4, q16 = lane & 15;
    int c0 = q16 * 4;

    float a0 = 0.f, a1 = 0.f, a2 = 0.f, a3 = 0.f;
    for (int base = beg; base < end; base += 64) {
        int m = min(64, end - base);
        int myS = (lane < m) ? csr_src[base + lane] : 0;
        float myN = (lane < m) ? dinv[myS] : 0.f;  // 0-weight for pad lanes
#pragma unroll 4
        for (int j4 = 0; j4 < m; j4 += 4) {
            int e = j4 + quad;                 // my edge in this group (may be >= m: nm=0)
            int s = __shfl(myS, e, 64);
            float nm = __shfl(myN, e, 64);
            ushort4 r = *(const ushort4*)(xw + (size_t)s * 64 + c0);
            a0 += bf2f(r.x) * nm;
            a1 += bf2f(r.y) * nm;
            a2 += bf2f(r.z) * nm;
            a3 += bf2f(r.w) * nm;
        }
    }
    // combine the 4 quad partial sums (each quad handled every 4th edge)
    a0 += __shfl_xor(a0, 16, 64); a0 += __shfl_xor(a0, 32, 64);
    a1 += __shfl_xor(a1, 16, 64); a1 += __shfl_xor(a1, 32, 64);
    a2 += __shfl_xor(a2, 16, 64); a2 += __shfl_xor(a2, 32, 64);
    a3 += __shfl_xor(a3, 16, 64); a3 += __shfl_xor(a3, 32, 64);

    float dd = dinv[node];
    ushort4 sr = *(const ushort4*)(xw + (size_t)node * 64 + c0);
    float y0 = a0 * dd + bf2f(sr.x) * dd * dd;
    float y1 = a1 * dd + bf2f(sr.y) * dd * dd;
    float y2 = a2 * dd + bf2f(sr.z) * dd * dd;
    float y3 = a3 * dd + bf2f(sr.w) * dd * dd;

    if (!LN) {
        if (quad == 0) {
            ushort4 o;
            o.x = f2bf(y0); o.y = f2bf(y1); o.z = f2bf(y2); o.w = f2bf(y3);
            *(ushort4*)(out + (size_t)node * 64 + c0) = o;
        }
        return;
    }
    float4 bv = *(const float4*)(bias + c0);
    float4 gv = *(const float4*)(gamma + c0);
    float4 tv = *(const float4*)(beta + c0);
    y0 += bv.x; y1 += bv.y; y2 += bv.z; y3 += bv.w;
    float s = y0 + y1 + y2 + y3;
    float sq = y0 * y0 + y1 * y1 + y2 * y2 + y3 * y3;
#pragma unroll
    for (int off = 1; off < 16; off <<= 1) {
        s += __shfl_xor(s, off, 64);
        sq += __shfl_xor(sq, off, 64);
    }
    float mu = s / 64.f;
    float var = sq / 64.f - mu * mu;
    float rs = rsqrtf(var + LN_EPS);
    float z0 = (y0 - mu) * rs * gv.x + tv.x; z0 = z0 > 0.f ? z0 : expm1f(z0);
    float z1 = (y1 - mu) * rs * gv.y + tv.y; z1 = z1 > 0.f ? z1 : expm1f(z1);
    float z2 = (y2 - mu) * rs * gv.z + tv.z; z2 = z2 > 0.f ? z2 : expm1f(z2);
    float z3 = (y3 - mu) * rs * gv.w + tv.w; z3 = z3 > 0.f ? z3 : expm1f(z3);
    if (quad == 0) {
        ushort4 o;
        o.x = f2bf(z0); o.y = f2bf(z1); o.z = f2bf(z2); o.w = f2bf(z3);
        *(ushort4*)(out + (size_t)node * 64 + c0) = o;
    }
}

extern "C" void kernel_launch(void* const* d_in, const int* in_sizes, int n_in,
                              void* d_out, int out_size, void* d_ws, size_t ws_size,
                              hipStream_t stream) {
    const float* x  = (const float*)d_in[0];
    const int* ei   = (const int*)d_in[1];
    const float* W1 = (const float*)d_in[2];
    const float* b1 = (const float*)d_in[3];
    const float* g1 = (const float*)d_in[4];
    const float* be1= (const float*)d_in[5];
    const float* W2 = (const float*)d_in[6];
    const float* b2 = (const float*)d_in[7];
    const float* g2 = (const float*)d_in[8];
    const float* be2= (const float*)d_in[9];
    const float* W3 = (const float*)d_in[10];
    const float* b3 = (const float*)d_in[11];
    const float* g3 = (const float*)d_in[12];
    const float* be3= (const float*)d_in[13];
    const float* lw1= (const float*)d_in[14];
    const float* lb1= (const float*)d_in[15];
    const float* g4 = (const float*)d_in[16];
    const float* be4= (const float*)d_in[17];
    const float* lw2= (const float*)d_in[18];
    const float* lb2= (const float*)d_in[19];
    float* out = (float*)d_out;

    const int E = in_sizes[1] / 2;
    const int* src = ei;
    const int* dst = ei + E;
    const int N = N_NODES;

    // workspace layout (intermediates in bf16)
    unsigned short* bufA = (unsigned short*)d_ws;       // N*128 bf16
    unsigned short* bufB = bufA + (size_t)N * 128;      // N*128 bf16
    float* dinv    = (float*)(bufB + (size_t)N * 128);  // N f32
    int*   deg     = (int*)(dinv + N);                  // N
    int*   offsets = deg + N;                           // N+1
    int*   cursor  = offsets + N + 1;                   // N
    int*   csr     = cursor + N;                        // E
    int*   bsums   = csr + E;                           // ceil(N/256)

    auto cdiv = [](long long a, long long b) { return (int)((a + b - 1) / b); };
    const int NB = cdiv(N, 256);
    const int GB = cdiv(N, 64);  // mfma gemm grid (64 rows/block)

    // ---- build CSR (dst-sorted) + dinv ----
    zero_int<<<NB, 256, 0, stream>>>(deg, N);
    hist_dst<<<cdiv(E, 256), 256, 0, stream>>>(dst, deg, E);
    scan_block_dinv<<<NB, 256, 0, stream>>>(deg, offsets, bsums, dinv, N);
    scan_sums_p<<<1, 512, 0, stream>>>(bsums, NB, offsets + N, E);
    scan_add_copy<<<NB, 256, 0, stream>>>(offsets, cursor, bsums, N);
    fill_csr<<<cdiv(E, 256), 256, 0, stream>>>(src, dst, cursor, csr, E);

    // ---- Layer 1: xw1 = x @ W1 (128->64, fp32 in); h1 = LN_ELU(gather + b1) ----
    mfma_gemm<128, 64, false, false, true, false><<<GB, 256, 0, stream>>>(
        x, W1, nullptr, nullptr, nullptr, bufA, N);
    gather64<true><<<cdiv(N, 4), 256, 0, stream>>>(bufA, offsets, csr, dinv, b1, g1, be1, bufB, N);

    // ---- Layer 2 (aggregate-first): a2 = gather(h1); h2 = LN_ELU(a2 @ W2 + b2) ----
    gather64<false><<<cdiv(N, 4), 256, 0, stream>>>(bufB, offsets, csr, dinv, nullptr, nullptr, nullptr, bufA, N);
    mfma_gemm<64, 128, true, true, false, false><<<GB, 256, 0, stream>>>(
        bufA, W2, b2, g2, be2, bufB, N);

    // ---- Layer 3: xw3 = h2 @ W3 (128->64); h3 = LN_ELU(gather + b3) ----
    mfma_gemm<128, 64, false, false, false, false><<<GB, 256, 0, stream>>>(
        bufB, W3, nullptr, nullptr, nullptr, bufA, N);
    gather64<true><<<cdiv(N, 4), 256, 0, stream>>>(bufA, offsets, csr, dinv, b3, g3, be3, bufB, N);

    // ---- lin1: t = LN_ELU(h3 @ lw1 + lb1) (64->32) ----
    mfma_gemm<64, 32, true, true, false, false><<<GB, 256, 0, stream>>>(
        bufB, lw1, lb1, g4, be4, bufA, N);

    // ---- lin2: out = t @ lw2 + lb2 (32->32, fp32 out) ----
    mfma_gemm<32, 32, false, true, false, true><<<GB, 256, 0, stream>>>(
        bufA, lw2, lb2, nullptr, nullptr, out, N);
}